// Round 1
// baseline (475.911 us; speedup 1.0000x reference)
//
#include <hip/hip_runtime.h>
#include <math.h>

#define Bsz 8
#define Cch 512
#define Npx 1024
#define TOPK 12

// ---------------- reduction helpers (blockDim.x == 256) ----------------
__device__ __forceinline__ float warp_sum64(float v) {
    for (int o = 32; o > 0; o >>= 1) v += __shfl_down(v, o);
    return v;
}
__device__ __forceinline__ float warp_max64(float v) {
    for (int o = 32; o > 0; o >>= 1) v = fmaxf(v, __shfl_down(v, o));
    return v;
}
__device__ __forceinline__ float block_sum256(float v, float* s4) {
    v = warp_sum64(v);
    int lane = threadIdx.x & 63, w = threadIdx.x >> 6;
    __syncthreads();
    if (lane == 0) s4[w] = v;
    __syncthreads();
    return s4[0] + s4[1] + s4[2] + s4[3];
}
__device__ __forceinline__ float block_max256(float v, float* s4) {
    v = warp_max64(v);
    int lane = threadIdx.x & 63, w = threadIdx.x >> 6;
    __syncthreads();
    if (lane == 0) s4[w] = v;
    __syncthreads();
    return fmaxf(fmaxf(s4[0], s4[1]), fmaxf(s4[2], s4[3]));
}

// ---------------- 1: masked average pool -> FP, BP ----------------
// grid (Cch, Bsz), block 256
__global__ void k_pool(const float* __restrict__ sf, const int* __restrict__ mask,
                       float* __restrict__ FPo, float* __restrict__ BPo) {
    __shared__ float s4[4];
    int c = blockIdx.x, b = blockIdx.y, t = threadIdx.x;
    const float* f = sf + ((size_t)b * Cch + c) * Npx;
    const int* m = mask + (size_t)b * Npx;
    float sumf = 0.f, sumb = 0.f, cf = 0.f, cb = 0.f;
    for (int p = t; p < Npx; p += 256) {
        float v = f[p];
        if (m[p] == 1) { sumf += v; cf += 1.f; }
        else           { sumb += v; cb += 1.f; }
    }
    sumf = block_sum256(sumf, s4);
    cf   = block_sum256(cf, s4);
    sumb = block_sum256(sumb, s4);
    cb   = block_sum256(cb, s4);
    if (t == 0) {
        FPo[b * Cch + c] = sumf / (cf + 1e-5f);
        BPo[b * Cch + c] = sumb / (cb + 1e-5f);
    }
}

// ---------------- 2: per-pixel 2-way similarity softmax ----------------
// grid (Npx/256, Bsz), block 256
__global__ void k_pred(const float* __restrict__ fq, const float* __restrict__ FP,
                       const float* __restrict__ BP, float* __restrict__ predf,
                       float* __restrict__ predb, float* __restrict__ invn) {
    __shared__ float sFP[Cch], sBP[Cch], s4[4];
    int b = blockIdx.y, t = threadIdx.x;
    int p = blockIdx.x * 256 + t;
    for (int c = t; c < Cch; c += 256) { sFP[c] = FP[b * Cch + c]; sBP[c] = BP[b * Cch + c]; }
    __syncthreads();
    float nf = 0.f, nb = 0.f;
    for (int c = t; c < Cch; c += 256) { nf += sFP[c] * sFP[c]; nb += sBP[c] * sBP[c]; }
    nf = sqrtf(block_sum256(nf, s4));
    nb = sqrtf(block_sum256(nb, s4));
    const float* q = fq + (size_t)b * Cch * Npx + p;
    float df = 0.f, db = 0.f, qq = 0.f;
    for (int c = 0; c < Cch; c++) {
        float v = q[(size_t)c * Npx];
        df += v * sFP[c]; db += v * sBP[c]; qq += v * v;
    }
    float nq = sqrtf(qq);
    float simf = 10.f * df / fmaxf(nq * nf, 1e-8f);
    float simb = 10.f * db / fmaxf(nq * nb, 1e-8f);
    // softmax over {simb, simf}
    float pf = 1.f / (1.f + expf(simb - simf));
    float pb = 1.f / (1.f + expf(simf - simb));
    predf[b * Npx + p] = pf;
    predb[b * Npx + p] = pb;
    invn[b * Npx + p] = 1.f / nq;
}

// ---------------- 3: select weights (threshold else top-12) ----------------
// grid Bsz, block 1024
__global__ void __launch_bounds__(1024) k_select(const float* __restrict__ pred, float thres,
                                                 float* __restrict__ w, float* __restrict__ cnt) {
    __shared__ float v[Npx];
    __shared__ float rv[Npx];
    __shared__ int   ri[Npx];
    __shared__ int   cnts;
    int b = blockIdx.x, t = threadIdx.x;
    float p = pred[b * Npx + t];
    int m = (p > thres) ? 1 : 0;
    if (t == 0) cnts = 0;
    __syncthreads();
    atomicAdd(&cnts, m);
    __syncthreads();
    if (cnts > 0) {
        w[b * Npx + t] = m ? 1.f : 0.f;
        if (t == 0) cnt[b] = (float)cnts;
    } else {
        v[t] = p;
        __syncthreads();
        float wv = 0.f;
        for (int k = 0; k < TOPK; k++) {
            rv[t] = v[t]; ri[t] = t;
            __syncthreads();
            for (int s = 512; s > 0; s >>= 1) {
                if (t < s) {
                    float a = rv[t], bb = rv[t + s];
                    int ia = ri[t], ib = ri[t + s];
                    if (bb > a || (bb == a && ib < ia)) { rv[t] = bb; ri[t] = ib; }
                }
                __syncthreads();
            }
            int win = ri[0];
            if (t == win) { wv = 1.f; v[t] = -INFINITY; }
            __syncthreads();
        }
        w[b * Npx + t] = wv;
        if (t == 0) cnt[b] = (float)TOPK;
    }
}

// ---------------- 4: weighted prototype ----------------
// grid (Cch, Bsz), block 256
__global__ void k_proto(const float* __restrict__ fq, const float* __restrict__ w,
                        const float* __restrict__ cnt, float* __restrict__ proto) {
    __shared__ float s4[4];
    int c = blockIdx.x, b = blockIdx.y, t = threadIdx.x;
    const float* f = fq + ((size_t)b * Cch + c) * Npx;
    const float* ww = w + (size_t)b * Npx;
    float s = 0.f;
    for (int p = t; p < Npx; p += 256) s += f[p] * ww[p];
    s = block_sum256(s, s4);
    if (t == 0) proto[b * Cch + c] = s / cnt[b];
}

// ---------------- 5: Gram matrix G[i,j] = sum_c F[c,i]F[c,j] ----------------
// grid (16,16,Bsz), block 256; 64x64 tile, BK=16, 4x4 per thread
__global__ void k_gram(const float* __restrict__ fq, float* __restrict__ G) {
    __shared__ float As[16][64];
    __shared__ float Bs[16][64];
    int b = blockIdx.z;
    int i0 = blockIdx.x * 64, j0 = blockIdx.y * 64;
    const float* F = fq + (size_t)b * Cch * Npx;
    int t = threadIdx.x;
    int tx = t & 15, ty = t >> 4;
    float acc[4][4] = {};
    for (int k0 = 0; k0 < Cch; k0 += 16) {
        #pragma unroll
        for (int s = 0; s < 4; s++) {
            int idx = t + s * 256;
            int k = idx >> 6, col = idx & 63;
            As[k][col] = F[(size_t)(k0 + k) * Npx + i0 + col];
            Bs[k][col] = F[(size_t)(k0 + k) * Npx + j0 + col];
        }
        __syncthreads();
        #pragma unroll
        for (int k = 0; k < 16; k++) {
            float a[4], bb[4];
            #pragma unroll
            for (int u = 0; u < 4; u++) { a[u] = As[k][ty * 4 + u]; bb[u] = Bs[k][tx * 4 + u]; }
            #pragma unroll
            for (int u = 0; u < 4; u++)
                #pragma unroll
                for (int vv = 0; vv < 4; vv++) acc[u][vv] += a[u] * bb[vv];
        }
        __syncthreads();
    }
    float* g = G + (size_t)b * Npx * Npx;
    #pragma unroll
    for (int u = 0; u < 4; u++)
        #pragma unroll
        for (int vv = 0; vv < 4; vv++)
            g[(size_t)(i0 + ty * 4 + u) * Npx + j0 + tx * 4 + vv] = acc[u][vv];
}

// ---------------- 6: masked row softmax in place ----------------
// grid (Npx, Bsz), block 256
__global__ void k_softmax(float* __restrict__ G, const float* __restrict__ invn,
                          const float* __restrict__ wb) {
    __shared__ float s4[4];
    int i = blockIdx.x, b = blockIdx.y, t = threadIdx.x;
    float* row = G + ((size_t)b * Npx + i) * Npx;
    const float* iv = invn + (size_t)b * Npx;
    const float* w = wb + (size_t)b * Npx;
    float ivi = iv[i];
    float vals[4];
    float mx = -INFINITY;
    #pragma unroll
    for (int q = 0; q < 4; q++) {
        int j = q * 256 + t;
        float s = 2.f * row[j] * ivi * iv[j];
        bool sel = w[j] > 0.f;
        float sv = sel ? s : -INFINITY;
        vals[q] = sv;
        mx = fmaxf(mx, sv);
    }
    mx = block_max256(mx, s4);
    float sum = 0.f;
    #pragma unroll
    for (int q = 0; q < 4; q++) { float e = expf(vals[q] - mx); vals[q] = e; sum += e; }
    sum = block_sum256(sum, s4);
    float inv = 1.f / sum;
    #pragma unroll
    for (int q = 0; q < 4; q++) row[q * 256 + t] = vals[q] * inv;
}

// ---------------- 7: bg_local[c,i] = sum_j attn[i,j] F[c,j] ----------------
// grid (16, 8, Bsz), block 256; 64(i) x 64(c) tile, BK=16
__global__ void k_pv(const float* __restrict__ fq, const float* __restrict__ A,
                     float* __restrict__ Dout) {
    __shared__ float As[16][65];   // As[kk][ii]
    __shared__ float Fs[16][65];   // Fs[kk][cc]
    int b = blockIdx.z;
    int i0 = blockIdx.x * 64, c0 = blockIdx.y * 64;
    const float* F = fq + (size_t)b * Cch * Npx;
    const float* At = A + (size_t)b * Npx * Npx;
    int t = threadIdx.x;
    int tx = t & 15, ty = t >> 4;
    float acc[4][4] = {};
    for (int j0 = 0; j0 < Npx; j0 += 16) {
        #pragma unroll
        for (int s = 0; s < 4; s++) {
            int idx = t + s * 256;
            int kk = idx & 15, r = idx >> 4;
            As[kk][r] = At[(size_t)(i0 + r) * Npx + j0 + kk];
            Fs[kk][r] = F[(size_t)(c0 + r) * Npx + j0 + kk];
        }
        __syncthreads();
        #pragma unroll
        for (int kk = 0; kk < 16; kk++) {
            float a[4], f[4];
            #pragma unroll
            for (int u = 0; u < 4; u++) { f[u] = Fs[kk][ty * 4 + u]; a[u] = As[kk][tx * 4 + u]; }
            #pragma unroll
            for (int u = 0; u < 4; u++)
                #pragma unroll
                for (int vv = 0; vv < 4; vv++) acc[u][vv] += f[u] * a[vv];
        }
        __syncthreads();
    }
    float* D = Dout + (size_t)b * Cch * Npx;
    #pragma unroll
    for (int u = 0; u < 4; u++)
        #pragma unroll
        for (int vv = 0; vv < 4; vv++)
            D[(size_t)(c0 + ty * 4 + u) * Npx + i0 + tx * 4 + vv] = acc[u][vv];
}

// ---------------- 8: final dual similarity ----------------
// grid (Npx/256, Bsz), block 256
__global__ void k_out(const float* __restrict__ fq, const float* __restrict__ FP,
                      const float* __restrict__ fgp, const float* __restrict__ bgp,
                      const float* __restrict__ local, float* __restrict__ out) {
    __shared__ float sFP1[Cch], sBG[Cch], s4[4];
    int b = blockIdx.y, t = threadIdx.x;
    int p = blockIdx.x * 256 + t;
    for (int c = t; c < Cch; c += 256) {
        sFP1[c] = 0.5f * FP[b * Cch + c] + 0.5f * fgp[b * Cch + c];
        sBG[c] = bgp[b * Cch + c];
    }
    __syncthreads();
    float nf = 0.f;
    for (int c = t; c < Cch; c += 256) nf += sFP1[c] * sFP1[c];
    nf = sqrtf(block_sum256(nf, s4));
    const float* q = fq + (size_t)b * Cch * Npx + p;
    const float* lo = local + (size_t)b * Cch * Npx + p;
    float df = 0.f, db = 0.f, qq = 0.f, nb2 = 0.f;
    for (int c = 0; c < Cch; c++) {
        float v = q[(size_t)c * Npx];
        float bp1 = 0.3f * sBG[c] + 0.7f * lo[(size_t)c * Npx];
        df += v * sFP1[c];
        db += v * bp1;
        qq += v * v;
        nb2 += bp1 * bp1;
    }
    float nq = sqrtf(qq);
    float sf = 10.f * df / fmaxf(nq * nf, 1e-8f);
    float sb = 10.f * db / fmaxf(nq * sqrtf(nb2), 1e-8f);
    out[((size_t)b * 2) * Npx + p] = sb;
    out[((size_t)b * 2 + 1) * Npx + p] = sf;
}

extern "C" void kernel_launch(void* const* d_in, const int* in_sizes, int n_in,
                              void* d_out, int out_size, void* d_ws, size_t ws_size,
                              hipStream_t stream) {
    const float* fq = (const float*)d_in[0];       // feature_q (B,C,H,W)
    const float* sf = (const float*)d_in[1];       // support_feat (B,C,H,W)
    const int* mask = (const int*)d_in[2];         // support_mask (B,H,W)
    float* out = (float*)d_out;

    float* ws = (float*)d_ws;
    float* FP    = ws;                       // B*C
    float* BP    = FP + Bsz * Cch;           // B*C
    float* fgp   = BP + Bsz * Cch;           // B*C
    float* bgp   = fgp + Bsz * Cch;          // B*C
    float* predf = bgp + Bsz * Cch;          // B*N
    float* predb = predf + Bsz * Npx;        // B*N
    float* invn  = predb + Bsz * Npx;        // B*N
    float* wf    = invn + Bsz * Npx;         // B*N
    float* wb    = wf + Bsz * Npx;           // B*N
    float* cnts  = wb + Bsz * Npx;           // 2*B
    float* G     = cnts + 2 * Bsz;           // B*N*N  (32 MB)
    float* local = G + (size_t)Bsz * Npx * Npx; // B*C*N (16 MB)

    k_pool<<<dim3(Cch, Bsz), 256, 0, stream>>>(sf, mask, FP, BP);
    k_pred<<<dim3(Npx / 256, Bsz), 256, 0, stream>>>(fq, FP, BP, predf, predb, invn);
    k_select<<<Bsz, 1024, 0, stream>>>(predf, 0.7f, wf, cnts);
    k_select<<<Bsz, 1024, 0, stream>>>(predb, 0.6f, wb, cnts + Bsz);
    k_proto<<<dim3(Cch, Bsz), 256, 0, stream>>>(fq, wf, cnts, fgp);
    k_proto<<<dim3(Cch, Bsz), 256, 0, stream>>>(fq, wb, cnts + Bsz, bgp);
    k_gram<<<dim3(16, 16, Bsz), 256, 0, stream>>>(fq, G);
    k_softmax<<<dim3(Npx, Bsz), 256, 0, stream>>>(G, invn, wb);
    k_pv<<<dim3(16, 8, Bsz), 256, 0, stream>>>(fq, G, local);
    k_out<<<dim3(Npx / 256, Bsz), 256, 0, stream>>>(fq, FP, fgp, bgp, local, out);
}

// Round 2
// 234.678 us; speedup vs baseline: 2.0279x; 2.0279x over previous
//
#include <hip/hip_runtime.h>
#include <math.h>

#define Bsz 8
#define Cch 512
#define Npx 1024
#define TOPK 12

typedef __attribute__((ext_vector_type(8))) short bf16x8;
typedef __attribute__((ext_vector_type(4))) float f32x4;

__device__ __forceinline__ unsigned short f2bf(float x) {
    unsigned u = __float_as_uint(x);
    u += 0x7FFF + ((u >> 16) & 1);
    return (unsigned short)(u >> 16);
}
__device__ __forceinline__ float bf2f(unsigned short h) {
    return __uint_as_float(((unsigned)h) << 16);
}

// ---------------- reduction helpers (blockDim.x == 256) ----------------
__device__ __forceinline__ float warp_sum64(float v) {
    for (int o = 32; o > 0; o >>= 1) v += __shfl_down(v, o);
    return v;
}
__device__ __forceinline__ float warp_max64(float v) {
    for (int o = 32; o > 0; o >>= 1) v = fmaxf(v, __shfl_down(v, o));
    return v;
}
__device__ __forceinline__ float block_sum256(float v, float* s4) {
    v = warp_sum64(v);
    int lane = threadIdx.x & 63, w = threadIdx.x >> 6;
    __syncthreads();
    if (lane == 0) s4[w] = v;
    __syncthreads();
    return s4[0] + s4[1] + s4[2] + s4[3];
}
__device__ __forceinline__ float block_max256(float v, float* s4) {
    v = warp_max64(v);
    int lane = threadIdx.x & 63, w = threadIdx.x >> 6;
    __syncthreads();
    if (lane == 0) s4[w] = v;
    __syncthreads();
    return fmaxf(fmaxf(s4[0], s4[1]), fmaxf(s4[2], s4[3]));
}

// ---------------- 1: masked average pool -> FP, BP ----------------
__global__ void k_pool(const float* __restrict__ sf, const int* __restrict__ mask,
                       float* __restrict__ FPo, float* __restrict__ BPo) {
    __shared__ float s4[4];
    int c = blockIdx.x, b = blockIdx.y, t = threadIdx.x;
    const float* f = sf + ((size_t)b * Cch + c) * Npx;
    const int* m = mask + (size_t)b * Npx;
    float sumf = 0.f, sumb = 0.f, cf = 0.f, cb = 0.f;
    for (int p = t; p < Npx; p += 256) {
        float v = f[p];
        if (m[p] == 1) { sumf += v; cf += 1.f; }
        else           { sumb += v; cb += 1.f; }
    }
    sumf = block_sum256(sumf, s4);
    cf   = block_sum256(cf, s4);
    sumb = block_sum256(sumb, s4);
    cb   = block_sum256(cb, s4);
    if (t == 0) {
        FPo[b * Cch + c] = sumf / (cf + 1e-5f);
        BPo[b * Cch + c] = sumb / (cb + 1e-5f);
    }
}

// ---------------- 2: per-pixel 2-way similarity softmax ----------------
__global__ void k_pred(const float* __restrict__ fq, const float* __restrict__ FP,
                       const float* __restrict__ BP, float* __restrict__ predf,
                       float* __restrict__ predb, float* __restrict__ invn) {
    __shared__ float sFP[Cch], sBP[Cch], s4[4];
    int b = blockIdx.y, t = threadIdx.x;
    int p = blockIdx.x * 256 + t;
    for (int c = t; c < Cch; c += 256) { sFP[c] = FP[b * Cch + c]; sBP[c] = BP[b * Cch + c]; }
    __syncthreads();
    float nf = 0.f, nb = 0.f;
    for (int c = t; c < Cch; c += 256) { nf += sFP[c] * sFP[c]; nb += sBP[c] * sBP[c]; }
    nf = sqrtf(block_sum256(nf, s4));
    nb = sqrtf(block_sum256(nb, s4));
    const float* q = fq + (size_t)b * Cch * Npx + p;
    float df = 0.f, db = 0.f, qq = 0.f;
    for (int c = 0; c < Cch; c++) {
        float v = q[(size_t)c * Npx];
        df += v * sFP[c]; db += v * sBP[c]; qq += v * v;
    }
    float nq = sqrtf(qq);
    float simf = 10.f * df / fmaxf(nq * nf, 1e-8f);
    float simb = 10.f * db / fmaxf(nq * nb, 1e-8f);
    float pf = 1.f / (1.f + expf(simb - simf));
    float pb = 1.f / (1.f + expf(simf - simb));
    predf[b * Npx + p] = pf;
    predb[b * Npx + p] = pb;
    invn[b * Npx + p] = 1.f / nq;
}

// ---------------- 3: select weights (threshold else top-12) ----------------
__global__ void __launch_bounds__(1024) k_select(const float* __restrict__ pred, float thres,
                                                 float* __restrict__ w, float* __restrict__ cnt) {
    __shared__ float v[Npx];
    __shared__ float rv[Npx];
    __shared__ int   ri[Npx];
    __shared__ int   cnts;
    int b = blockIdx.x, t = threadIdx.x;
    float p = pred[b * Npx + t];
    int m = (p > thres) ? 1 : 0;
    if (t == 0) cnts = 0;
    __syncthreads();
    atomicAdd(&cnts, m);
    __syncthreads();
    if (cnts > 0) {
        w[b * Npx + t] = m ? 1.f : 0.f;
        if (t == 0) cnt[b] = (float)cnts;
    } else {
        v[t] = p;
        __syncthreads();
        float wv = 0.f;
        for (int k = 0; k < TOPK; k++) {
            rv[t] = v[t]; ri[t] = t;
            __syncthreads();
            for (int s = 512; s > 0; s >>= 1) {
                if (t < s) {
                    float a = rv[t], bb = rv[t + s];
                    int ia = ri[t], ib = ri[t + s];
                    if (bb > a || (bb == a && ib < ia)) { rv[t] = bb; ri[t] = ib; }
                }
                __syncthreads();
            }
            int win = ri[0];
            if (t == win) { wv = 1.f; v[t] = -INFINITY; }
            __syncthreads();
        }
        w[b * Npx + t] = wv;
        if (t == 0) cnt[b] = (float)TOPK;
    }
}

// ---------------- 4: weighted prototype ----------------
__global__ void k_proto(const float* __restrict__ fq, const float* __restrict__ w,
                        const float* __restrict__ cnt, float* __restrict__ proto) {
    __shared__ float s4[4];
    int c = blockIdx.x, b = blockIdx.y, t = threadIdx.x;
    const float* f = fq + ((size_t)b * Cch + c) * Npx;
    const float* ww = w + (size_t)b * Npx;
    float s = 0.f;
    for (int p = t; p < Npx; p += 256) s += f[p] * ww[p];
    s = block_sum256(s, s4);
    if (t == 0) proto[b * Cch + c] = s / cnt[b];
}

// ---------------- 4b: bf16 cast + transpose ----------------
// Fc[b][c][i] = bf16(fq[b][c][i]);  Ft[b][i][c] = bf16(fq[b][c][i])
// grid (Npx/32, Cch/32, Bsz), block 256
__global__ void k_cast(const float* __restrict__ fq, unsigned short* __restrict__ Fc,
                       unsigned short* __restrict__ Ft) {
    __shared__ unsigned short tt[32][33];
    int b = blockIdx.z;
    int i0 = blockIdx.x * 32, c0 = blockIdx.y * 32;
    int tid = threadIdx.x;
    int col = tid & 31, rr = tid >> 5;
    const float* F = fq + (size_t)b * Cch * Npx;
    unsigned short* FcB = Fc + (size_t)b * Cch * Npx;
    unsigned short* FtB = Ft + (size_t)b * Npx * Cch;
    for (int r = rr; r < 32; r += 8) {
        float v = F[(size_t)(c0 + r) * Npx + i0 + col];
        unsigned short h = f2bf(v);
        FcB[(size_t)(c0 + r) * Npx + i0 + col] = h;
        tt[r][col] = h;
    }
    __syncthreads();
    for (int r = rr; r < 32; r += 8) {
        FtB[(size_t)(i0 + r) * Cch + c0 + col] = tt[col][r];
    }
}

// ---------------- 5: Gram via MFMA: G[i,j] = sum_c Ft[i,c]*Ft[j,c], bf16 out --
// grid (Npx/128, Npx/128, Bsz), block 256 (4 waves, each 64x64)
__global__ void __launch_bounds__(256) k_gram_mfma(const unsigned short* __restrict__ Ft,
                                                   unsigned short* __restrict__ G) {
    __shared__ unsigned short At[128][40];   // pad to 40 halves: frag reads 2-way/bank
    __shared__ unsigned short Bt[128][40];
    int b = blockIdx.z;
    int i0 = blockIdx.x * 128, j0 = blockIdx.y * 128;
    const unsigned short* F = Ft + (size_t)b * Npx * Cch;
    int tid = threadIdx.x;
    int l = tid & 63, w = tid >> 6;
    int ml = l & 15, quad = l >> 4;
    int wi = (w & 1) * 64, wj = (w >> 1) * 64;
    f32x4 acc[4][4] = {};
    for (int k0 = 0; k0 < Cch; k0 += 32) {
        #pragma unroll
        for (int s = 0; s < 2; s++) {
            int idx = tid + s * 256;
            int r = idx >> 2, kc = idx & 3;
            *(uint4*)&At[r][kc * 8] = *(const uint4*)(F + (size_t)(i0 + r) * Cch + k0 + kc * 8);
            *(uint4*)&Bt[r][kc * 8] = *(const uint4*)(F + (size_t)(j0 + r) * Cch + k0 + kc * 8);
        }
        __syncthreads();
        bf16x8 af[4], bfr[4];
        #pragma unroll
        for (int u = 0; u < 4; u++) af[u] = *(const bf16x8*)&At[wi + u * 16 + ml][quad * 8];
        #pragma unroll
        for (int v = 0; v < 4; v++) bfr[v] = *(const bf16x8*)&Bt[wj + v * 16 + ml][quad * 8];
        #pragma unroll
        for (int u = 0; u < 4; u++)
            #pragma unroll
            for (int v = 0; v < 4; v++)
                acc[u][v] = __builtin_amdgcn_mfma_f32_16x16x32_bf16(af[u], bfr[v], acc[u][v], 0, 0, 0);
        __syncthreads();
    }
    unsigned short* g = G + (size_t)b * Npx * Npx;
    #pragma unroll
    for (int u = 0; u < 4; u++) {
        int i = i0 + wi + u * 16 + quad * 4;
        #pragma unroll
        for (int v = 0; v < 4; v++) {
            int j = j0 + wj + v * 16 + ml;
            #pragma unroll
            for (int r = 0; r < 4; r++)
                g[(size_t)(i + r) * Npx + j] = f2bf(acc[u][v][r]);
        }
    }
}

// ---------------- 6: masked row softmax, bf16 in place ----------------
// grid (Npx, Bsz), block 256
__global__ void k_softmax(unsigned short* __restrict__ G, const float* __restrict__ invn,
                          const float* __restrict__ wb) {
    __shared__ float s4[4];
    int i = blockIdx.x, b = blockIdx.y, t = threadIdx.x;
    unsigned short* row = G + ((size_t)b * Npx + i) * Npx;
    const float* iv = invn + (size_t)b * Npx;
    const float* w = wb + (size_t)b * Npx;
    float ivi = iv[i];
    float vals[4];
    float mx = -INFINITY;
    #pragma unroll
    for (int q = 0; q < 4; q++) {
        int j = q * 256 + t;
        float s = 2.f * bf2f(row[j]) * ivi * iv[j];
        bool sel = w[j] > 0.f;
        float sv = sel ? s : -INFINITY;
        vals[q] = sv;
        mx = fmaxf(mx, sv);
    }
    mx = block_max256(mx, s4);   // contains __syncthreads: all reads done before writes
    float sum = 0.f;
    #pragma unroll
    for (int q = 0; q < 4; q++) { float e = expf(vals[q] - mx); vals[q] = e; sum += e; }
    sum = block_sum256(sum, s4);
    float inv = 1.f / sum;
    #pragma unroll
    for (int q = 0; q < 4; q++) row[q * 256 + t] = f2bf(vals[q] * inv);
}

// ---------------- 7: PV via MFMA: local[c,i] = sum_j attn[i,j] Fc[c,j] --------
// grid (Npx/128, Cch/64, Bsz), block 256; waves 2(c)x2(i), each 32x64
__global__ void __launch_bounds__(256) k_pv_mfma(const unsigned short* __restrict__ Fc,
                                                 const unsigned short* __restrict__ A,
                                                 float* __restrict__ Dout) {
    __shared__ unsigned short At[64][40];
    __shared__ unsigned short Bt[128][40];
    int b = blockIdx.z;
    int i0 = blockIdx.x * 128, c0 = blockIdx.y * 64;
    const unsigned short* F = Fc + (size_t)b * Cch * Npx;
    const unsigned short* Ar = A + (size_t)b * Npx * Npx;
    int tid = threadIdx.x;
    int l = tid & 63, w = tid >> 6;
    int ml = l & 15, quad = l >> 4;
    int wm = (w & 1) * 32, wn = (w >> 1) * 64;
    f32x4 acc[2][4] = {};
    for (int j0 = 0; j0 < Npx; j0 += 32) {
        {
            int r = tid >> 2, kc = tid & 3;
            *(uint4*)&At[r][kc * 8] = *(const uint4*)(F + (size_t)(c0 + r) * Npx + j0 + kc * 8);
        }
        #pragma unroll
        for (int s = 0; s < 2; s++) {
            int idx = tid + s * 256;
            int r = idx >> 2, kc = idx & 3;
            *(uint4*)&Bt[r][kc * 8] = *(const uint4*)(Ar + (size_t)(i0 + r) * Npx + j0 + kc * 8);
        }
        __syncthreads();
        bf16x8 af[2], bfr[4];
        #pragma unroll
        for (int u = 0; u < 2; u++) af[u] = *(const bf16x8*)&At[wm + u * 16 + ml][quad * 8];
        #pragma unroll
        for (int v = 0; v < 4; v++) bfr[v] = *(const bf16x8*)&Bt[wn + v * 16 + ml][quad * 8];
        #pragma unroll
        for (int u = 0; u < 2; u++)
            #pragma unroll
            for (int v = 0; v < 4; v++)
                acc[u][v] = __builtin_amdgcn_mfma_f32_16x16x32_bf16(af[u], bfr[v], acc[u][v], 0, 0, 0);
        __syncthreads();
    }
    float* D = Dout + (size_t)b * Cch * Npx;
    #pragma unroll
    for (int u = 0; u < 2; u++) {
        int c = c0 + wm + u * 16 + quad * 4;
        #pragma unroll
        for (int v = 0; v < 4; v++) {
            int i = i0 + wn + v * 16 + ml;
            #pragma unroll
            for (int r = 0; r < 4; r++)
                D[(size_t)(c + r) * Npx + i] = acc[u][v][r];
        }
    }
}

// ---------------- 8: final dual similarity ----------------
__global__ void k_out(const float* __restrict__ fq, const float* __restrict__ FP,
                      const float* __restrict__ fgp, const float* __restrict__ bgp,
                      const float* __restrict__ local, float* __restrict__ out) {
    __shared__ float sFP1[Cch], sBG[Cch], s4[4];
    int b = blockIdx.y, t = threadIdx.x;
    int p = blockIdx.x * 256 + t;
    for (int c = t; c < Cch; c += 256) {
        sFP1[c] = 0.5f * FP[b * Cch + c] + 0.5f * fgp[b * Cch + c];
        sBG[c] = bgp[b * Cch + c];
    }
    __syncthreads();
    float nf = 0.f;
    for (int c = t; c < Cch; c += 256) nf += sFP1[c] * sFP1[c];
    nf = sqrtf(block_sum256(nf, s4));
    const float* q = fq + (size_t)b * Cch * Npx + p;
    const float* lo = local + (size_t)b * Cch * Npx + p;
    float df = 0.f, db = 0.f, qq = 0.f, nb2 = 0.f;
    for (int c = 0; c < Cch; c++) {
        float v = q[(size_t)c * Npx];
        float bp1 = 0.3f * sBG[c] + 0.7f * lo[(size_t)c * Npx];
        df += v * sFP1[c];
        db += v * bp1;
        qq += v * v;
        nb2 += bp1 * bp1;
    }
    float nq = sqrtf(qq);
    float sf = 10.f * df / fmaxf(nq * nf, 1e-8f);
    float sb = 10.f * db / fmaxf(nq * sqrtf(nb2), 1e-8f);
    out[((size_t)b * 2) * Npx + p] = sb;
    out[((size_t)b * 2 + 1) * Npx + p] = sf;
}

extern "C" void kernel_launch(void* const* d_in, const int* in_sizes, int n_in,
                              void* d_out, int out_size, void* d_ws, size_t ws_size,
                              hipStream_t stream) {
    const float* fq = (const float*)d_in[0];
    const float* sf = (const float*)d_in[1];
    const int* mask = (const int*)d_in[2];
    float* out = (float*)d_out;

    float* ws = (float*)d_ws;
    float* FP    = ws;                       // B*C
    float* BP    = FP + Bsz * Cch;
    float* fgp   = BP + Bsz * Cch;
    float* bgp   = fgp + Bsz * Cch;
    float* predf = bgp + Bsz * Cch;          // B*N
    float* predb = predf + Bsz * Npx;
    float* invn  = predb + Bsz * Npx;
    float* wf    = invn + Bsz * Npx;
    float* wb    = wf + Bsz * Npx;
    float* cnts  = wb + Bsz * Npx;           // 16
    unsigned short* Gb = (unsigned short*)(cnts + 16);          // B*N*N bf16 (16 MB)
    float* local = (float*)(Gb + (size_t)Bsz * Npx * Npx);      // B*C*N f32 (16 MB)
    unsigned short* Ft = (unsigned short*)(local + (size_t)Bsz * Cch * Npx);  // 8 MB
    unsigned short* Fc = Ft + (size_t)Bsz * Npx * Cch;                        // 8 MB
    // total = 50,561,088 B == round-1 footprint

    k_pool<<<dim3(Cch, Bsz), 256, 0, stream>>>(sf, mask, FP, BP);
    k_pred<<<dim3(Npx / 256, Bsz), 256, 0, stream>>>(fq, FP, BP, predf, predb, invn);
    k_select<<<Bsz, 1024, 0, stream>>>(predf, 0.7f, wf, cnts);
    k_select<<<Bsz, 1024, 0, stream>>>(predb, 0.6f, wb, cnts + Bsz);
    k_proto<<<dim3(Cch, Bsz), 256, 0, stream>>>(fq, wf, cnts, fgp);
    k_proto<<<dim3(Cch, Bsz), 256, 0, stream>>>(fq, wb, cnts + Bsz, bgp);
    k_cast<<<dim3(Npx / 32, Cch / 32, Bsz), 256, 0, stream>>>(fq, Fc, Ft);
    k_gram_mfma<<<dim3(Npx / 128, Npx / 128, Bsz), 256, 0, stream>>>(Ft, Gb);
    k_softmax<<<dim3(Npx, Bsz), 256, 0, stream>>>(Gb, invn, wb);
    k_pv_mfma<<<dim3(Npx / 128, Cch / 64, Bsz), 256, 0, stream>>>(Fc, Gb, local);
    k_out<<<dim3(Npx / 256, Bsz), 256, 0, stream>>>(fq, FP, fgp, bgp, local, out);
}

// Round 3
// 175.360 us; speedup vs baseline: 2.7139x; 1.3383x over previous
//
#include <hip/hip_runtime.h>
#include <math.h>

#define Bsz 8
#define Cch 512
#define Npx 1024
#define TOPK 12

typedef __attribute__((ext_vector_type(8))) short bf16x8;
typedef __attribute__((ext_vector_type(4))) float f32x4;

__device__ __forceinline__ unsigned short f2bf(float x) {
    unsigned u = __float_as_uint(x);
    u += 0x7FFF + ((u >> 16) & 1);
    return (unsigned short)(u >> 16);
}
__device__ __forceinline__ float bf2f(unsigned short h) {
    return __uint_as_float(((unsigned)h) << 16);
}

// ---------------- reduction helpers (blockDim.x == 256) ----------------
__device__ __forceinline__ float warp_sum64(float v) {
    for (int o = 32; o > 0; o >>= 1) v += __shfl_down(v, o);
    return v;
}
__device__ __forceinline__ float warp_max64(float v) {
    for (int o = 32; o > 0; o >>= 1) v = fmaxf(v, __shfl_down(v, o));
    return v;
}
__device__ __forceinline__ float block_sum256(float v, float* s4) {
    v = warp_sum64(v);
    int lane = threadIdx.x & 63, w = threadIdx.x >> 6;
    __syncthreads();
    if (lane == 0) s4[w] = v;
    __syncthreads();
    return s4[0] + s4[1] + s4[2] + s4[3];
}
__device__ __forceinline__ float block_max256(float v, float* s4) {
    v = warp_max64(v);
    int lane = threadIdx.x & 63, w = threadIdx.x >> 6;
    __syncthreads();
    if (lane == 0) s4[w] = v;
    __syncthreads();
    return fmaxf(fmaxf(s4[0], s4[1]), fmaxf(s4[2], s4[3]));
}

// ---------------- 1: masked average pool -> FP, BP ----------------
__global__ void k_pool(const float* __restrict__ sf, const int* __restrict__ mask,
                       float* __restrict__ FPo, float* __restrict__ BPo) {
    __shared__ float s4[4];
    int c = blockIdx.x, b = blockIdx.y, t = threadIdx.x;
    const float* f = sf + ((size_t)b * Cch + c) * Npx;
    const int* m = mask + (size_t)b * Npx;
    float sumf = 0.f, sumb = 0.f, cf = 0.f, cb = 0.f;
    for (int p = t; p < Npx; p += 256) {
        float v = f[p];
        if (m[p] == 1) { sumf += v; cf += 1.f; }
        else           { sumb += v; cb += 1.f; }
    }
    sumf = block_sum256(sumf, s4);
    cf   = block_sum256(cf, s4);
    sumb = block_sum256(sumb, s4);
    cb   = block_sum256(cb, s4);
    if (t == 0) {
        FPo[b * Cch + c] = sumf / (cf + 1e-5f);
        BPo[b * Cch + c] = sumb / (cb + 1e-5f);
    }
}

// ---------------- 2: per-pixel 2-way similarity softmax ----------------
// grid (Npx/32, Bsz), block 256: 32 pixels/block, 8 threads/pixel (64 ch each)
__global__ void k_pred(const float* __restrict__ fq, const float* __restrict__ FP,
                       const float* __restrict__ BP, float* __restrict__ predf,
                       float* __restrict__ predb, float* __restrict__ invn) {
    __shared__ float sFP[Cch], sBP[Cch], s4[4];
    __shared__ float rdf[8][32], rdb[8][32], rqq[8][32];
    int b = blockIdx.y, t = threadIdx.x;
    int tx = t & 31, ty = t >> 5;
    int p = blockIdx.x * 32 + tx;
    for (int c = t; c < Cch; c += 256) { sFP[c] = FP[b * Cch + c]; sBP[c] = BP[b * Cch + c]; }
    __syncthreads();
    float nf = 0.f, nb = 0.f;
    for (int c = t; c < Cch; c += 256) { nf += sFP[c] * sFP[c]; nb += sBP[c] * sBP[c]; }
    nf = sqrtf(block_sum256(nf, s4));
    nb = sqrtf(block_sum256(nb, s4));
    const float* q = fq + (size_t)b * Cch * Npx + p;
    float df = 0.f, db = 0.f, qq = 0.f;
    int c0 = ty * 64;
    #pragma unroll 4
    for (int c = 0; c < 64; c++) {
        float v = q[(size_t)(c0 + c) * Npx];
        df += v * sFP[c0 + c]; db += v * sBP[c0 + c]; qq += v * v;
    }
    rdf[ty][tx] = df; rdb[ty][tx] = db; rqq[ty][tx] = qq;
    __syncthreads();
    for (int s = 4; s > 0; s >>= 1) {
        if (ty < s) {
            rdf[ty][tx] += rdf[ty + s][tx];
            rdb[ty][tx] += rdb[ty + s][tx];
            rqq[ty][tx] += rqq[ty + s][tx];
        }
        __syncthreads();
    }
    if (ty == 0) {
        float nq = sqrtf(rqq[0][tx]);
        float simf = 10.f * rdf[0][tx] / fmaxf(nq * nf, 1e-8f);
        float simb = 10.f * rdb[0][tx] / fmaxf(nq * nb, 1e-8f);
        predf[b * Npx + p] = 1.f / (1.f + expf(simb - simf));
        predb[b * Npx + p] = 1.f / (1.f + expf(simf - simb));
        invn[b * Npx + p] = 1.f / nq;
    }
}

// ---------------- 3: select weights (threshold else top-12) ----------------
__global__ void __launch_bounds__(1024) k_select(const float* __restrict__ pred, float thres,
                                                 float* __restrict__ w, float* __restrict__ cnt) {
    __shared__ float v[Npx];
    __shared__ float rv[Npx];
    __shared__ int   ri[Npx];
    __shared__ int   cnts;
    int b = blockIdx.x, t = threadIdx.x;
    float p = pred[b * Npx + t];
    int m = (p > thres) ? 1 : 0;
    if (t == 0) cnts = 0;
    __syncthreads();
    atomicAdd(&cnts, m);
    __syncthreads();
    if (cnts > 0) {
        w[b * Npx + t] = m ? 1.f : 0.f;
        if (t == 0) cnt[b] = (float)cnts;
    } else {
        v[t] = p;
        __syncthreads();
        float wv = 0.f;
        for (int k = 0; k < TOPK; k++) {
            rv[t] = v[t]; ri[t] = t;
            __syncthreads();
            for (int s = 512; s > 0; s >>= 1) {
                if (t < s) {
                    float a = rv[t], bb = rv[t + s];
                    int ia = ri[t], ib = ri[t + s];
                    if (bb > a || (bb == a && ib < ia)) { rv[t] = bb; ri[t] = ib; }
                }
                __syncthreads();
            }
            int win = ri[0];
            if (t == win) { wv = 1.f; v[t] = -INFINITY; }
            __syncthreads();
        }
        w[b * Npx + t] = wv;
        if (t == 0) cnt[b] = (float)TOPK;
    }
}

// ---------------- 4: both weighted prototypes in one pass ----------------
// grid (Cch, Bsz), block 256
__global__ void k_proto2(const float* __restrict__ fq, const float* __restrict__ wf,
                         const float* __restrict__ wb, const float* __restrict__ cnt,
                         float* __restrict__ fgp, float* __restrict__ bgp) {
    __shared__ float s4[4];
    int c = blockIdx.x, b = blockIdx.y, t = threadIdx.x;
    const float* f = fq + ((size_t)b * Cch + c) * Npx;
    const float* wwf = wf + (size_t)b * Npx;
    const float* wwb = wb + (size_t)b * Npx;
    float sf_ = 0.f, sb_ = 0.f;
    for (int p = t; p < Npx; p += 256) {
        float v = f[p];
        sf_ += v * wwf[p];
        sb_ += v * wwb[p];
    }
    sf_ = block_sum256(sf_, s4);
    sb_ = block_sum256(sb_, s4);
    if (t == 0) {
        fgp[b * Cch + c] = sf_ / cnt[b];
        bgp[b * Cch + c] = sb_ / cnt[Bsz + b];
    }
}

// ---------------- 4b: bf16 cast + transpose ----------------
__global__ void k_cast(const float* __restrict__ fq, unsigned short* __restrict__ Fc,
                       unsigned short* __restrict__ Ft) {
    __shared__ unsigned short tt[32][33];
    int b = blockIdx.z;
    int i0 = blockIdx.x * 32, c0 = blockIdx.y * 32;
    int tid = threadIdx.x;
    int col = tid & 31, rr = tid >> 5;
    const float* F = fq + (size_t)b * Cch * Npx;
    unsigned short* FcB = Fc + (size_t)b * Cch * Npx;
    unsigned short* FtB = Ft + (size_t)b * Npx * Cch;
    for (int r = rr; r < 32; r += 8) {
        float v = F[(size_t)(c0 + r) * Npx + i0 + col];
        unsigned short h = f2bf(v);
        FcB[(size_t)(c0 + r) * Npx + i0 + col] = h;
        tt[r][col] = h;
    }
    __syncthreads();
    for (int r = rr; r < 32; r += 8) {
        FtB[(size_t)(i0 + r) * Cch + c0 + col] = tt[col][r];
    }
}

// ---------------- 5: Gram via MFMA ----------------
__global__ void __launch_bounds__(256) k_gram_mfma(const unsigned short* __restrict__ Ft,
                                                   unsigned short* __restrict__ G) {
    __shared__ unsigned short At[128][40];
    __shared__ unsigned short Bt[128][40];
    int b = blockIdx.z;
    int i0 = blockIdx.x * 128, j0 = blockIdx.y * 128;
    const unsigned short* F = Ft + (size_t)b * Npx * Cch;
    int tid = threadIdx.x;
    int l = tid & 63, w = tid >> 6;
    int ml = l & 15, quad = l >> 4;
    int wi = (w & 1) * 64, wj = (w >> 1) * 64;
    f32x4 acc[4][4] = {};
    for (int k0 = 0; k0 < Cch; k0 += 32) {
        #pragma unroll
        for (int s = 0; s < 2; s++) {
            int idx = tid + s * 256;
            int r = idx >> 2, kc = idx & 3;
            *(uint4*)&At[r][kc * 8] = *(const uint4*)(F + (size_t)(i0 + r) * Cch + k0 + kc * 8);
            *(uint4*)&Bt[r][kc * 8] = *(const uint4*)(F + (size_t)(j0 + r) * Cch + k0 + kc * 8);
        }
        __syncthreads();
        bf16x8 af[4], bfr[4];
        #pragma unroll
        for (int u = 0; u < 4; u++) af[u] = *(const bf16x8*)&At[wi + u * 16 + ml][quad * 8];
        #pragma unroll
        for (int v = 0; v < 4; v++) bfr[v] = *(const bf16x8*)&Bt[wj + v * 16 + ml][quad * 8];
        #pragma unroll
        for (int u = 0; u < 4; u++)
            #pragma unroll
            for (int v = 0; v < 4; v++)
                acc[u][v] = __builtin_amdgcn_mfma_f32_16x16x32_bf16(af[u], bfr[v], acc[u][v], 0, 0, 0);
        __syncthreads();
    }
    unsigned short* g = G + (size_t)b * Npx * Npx;
    #pragma unroll
    for (int u = 0; u < 4; u++) {
        int i = i0 + wi + u * 16 + quad * 4;
        #pragma unroll
        for (int v = 0; v < 4; v++) {
            int j = j0 + wj + v * 16 + ml;
            #pragma unroll
            for (int r = 0; r < 4; r++)
                g[(size_t)(i + r) * Npx + j] = f2bf(acc[u][v][r]);
        }
    }
}

// ---------------- 6: masked row softmax, bf16 in place ----------------
__global__ void k_softmax(unsigned short* __restrict__ G, const float* __restrict__ invn,
                          const float* __restrict__ wb) {
    __shared__ float s4[4];
    int i = blockIdx.x, b = blockIdx.y, t = threadIdx.x;
    unsigned short* row = G + ((size_t)b * Npx + i) * Npx;
    const float* iv = invn + (size_t)b * Npx;
    const float* w = wb + (size_t)b * Npx;
    float ivi = iv[i];
    float vals[4];
    float mx = -INFINITY;
    #pragma unroll
    for (int q = 0; q < 4; q++) {
        int j = q * 256 + t;
        float s = 2.f * bf2f(row[j]) * ivi * iv[j];
        bool sel = w[j] > 0.f;
        float sv = sel ? s : -INFINITY;
        vals[q] = sv;
        mx = fmaxf(mx, sv);
    }
    mx = block_max256(mx, s4);
    float sum = 0.f;
    #pragma unroll
    for (int q = 0; q < 4; q++) { float e = expf(vals[q] - mx); vals[q] = e; sum += e; }
    sum = block_sum256(sum, s4);
    float inv = 1.f / sum;
    #pragma unroll
    for (int q = 0; q < 4; q++) row[q * 256 + t] = f2bf(vals[q] * inv);
}

// ---------------- 7: PV via MFMA ----------------
__global__ void __launch_bounds__(256) k_pv_mfma(const unsigned short* __restrict__ Fc,
                                                 const unsigned short* __restrict__ A,
                                                 float* __restrict__ Dout) {
    __shared__ unsigned short At[64][40];
    __shared__ unsigned short Bt[128][40];
    int b = blockIdx.z;
    int i0 = blockIdx.x * 128, c0 = blockIdx.y * 64;
    const unsigned short* F = Fc + (size_t)b * Cch * Npx;
    const unsigned short* Ar = A + (size_t)b * Npx * Npx;
    int tid = threadIdx.x;
    int l = tid & 63, w = tid >> 6;
    int ml = l & 15, quad = l >> 4;
    int wm = (w & 1) * 32, wn = (w >> 1) * 64;
    f32x4 acc[2][4] = {};
    for (int j0 = 0; j0 < Npx; j0 += 32) {
        {
            int r = tid >> 2, kc = tid & 3;
            *(uint4*)&At[r][kc * 8] = *(const uint4*)(F + (size_t)(c0 + r) * Npx + j0 + kc * 8);
        }
        #pragma unroll
        for (int s = 0; s < 2; s++) {
            int idx = tid + s * 256;
            int r = idx >> 2, kc = idx & 3;
            *(uint4*)&Bt[r][kc * 8] = *(const uint4*)(Ar + (size_t)(i0 + r) * Npx + j0 + kc * 8);
        }
        __syncthreads();
        bf16x8 af[2], bfr[4];
        #pragma unroll
        for (int u = 0; u < 2; u++) af[u] = *(const bf16x8*)&At[wm + u * 16 + ml][quad * 8];
        #pragma unroll
        for (int v = 0; v < 4; v++) bfr[v] = *(const bf16x8*)&Bt[wn + v * 16 + ml][quad * 8];
        #pragma unroll
        for (int u = 0; u < 2; u++)
            #pragma unroll
            for (int v = 0; v < 4; v++)
                acc[u][v] = __builtin_amdgcn_mfma_f32_16x16x32_bf16(af[u], bfr[v], acc[u][v], 0, 0, 0);
        __syncthreads();
    }
    float* D = Dout + (size_t)b * Cch * Npx;
    #pragma unroll
    for (int u = 0; u < 2; u++) {
        int c = c0 + wm + u * 16 + quad * 4;
        #pragma unroll
        for (int v = 0; v < 4; v++) {
            int i = i0 + wn + v * 16 + ml;
            #pragma unroll
            for (int r = 0; r < 4; r++)
                D[(size_t)(c + r) * Npx + i] = acc[u][v][r];
        }
    }
}

// ---------------- 8: final dual similarity ----------------
// grid (Npx/32, Bsz), block 256: 32 pixels/block, 8 threads/pixel (64 ch each)
__global__ void k_out(const float* __restrict__ fq, const float* __restrict__ FP,
                      const float* __restrict__ fgp, const float* __restrict__ bgp,
                      const float* __restrict__ local, float* __restrict__ out) {
    __shared__ float sFP1[Cch], sBG[Cch], s4[4];
    __shared__ float rdf[8][32], rdb[8][32], rqq[8][32], rnb[8][32];
    int b = blockIdx.y, t = threadIdx.x;
    int tx = t & 31, ty = t >> 5;
    int p = blockIdx.x * 32 + tx;
    for (int c = t; c < Cch; c += 256) {
        sFP1[c] = 0.5f * FP[b * Cch + c] + 0.5f * fgp[b * Cch + c];
        sBG[c] = 0.3f * bgp[b * Cch + c];
    }
    __syncthreads();
    float nf = 0.f;
    for (int c = t; c < Cch; c += 256) nf += sFP1[c] * sFP1[c];
    nf = sqrtf(block_sum256(nf, s4));
    const float* q = fq + (size_t)b * Cch * Npx + p;
    const float* lo = local + (size_t)b * Cch * Npx + p;
    float df = 0.f, db = 0.f, qq = 0.f, nb2 = 0.f;
    int c0 = ty * 64;
    #pragma unroll 4
    for (int c = 0; c < 64; c++) {
        float v = q[(size_t)(c0 + c) * Npx];
        float bp1 = sBG[c0 + c] + 0.7f * lo[(size_t)(c0 + c) * Npx];
        df += v * sFP1[c0 + c];
        db += v * bp1;
        qq += v * v;
        nb2 += bp1 * bp1;
    }
    rdf[ty][tx] = df; rdb[ty][tx] = db; rqq[ty][tx] = qq; rnb[ty][tx] = nb2;
    __syncthreads();
    for (int s = 4; s > 0; s >>= 1) {
        if (ty < s) {
            rdf[ty][tx] += rdf[ty + s][tx];
            rdb[ty][tx] += rdb[ty + s][tx];
            rqq[ty][tx] += rqq[ty + s][tx];
            rnb[ty][tx] += rnb[ty + s][tx];
        }
        __syncthreads();
    }
    if (ty == 0) {
        float nq = sqrtf(rqq[0][tx]);
        float sf = 10.f * rdf[0][tx] / fmaxf(nq * nf, 1e-8f);
        float sb = 10.f * rdb[0][tx] / fmaxf(nq * sqrtf(rnb[0][tx]), 1e-8f);
        out[((size_t)b * 2) * Npx + p] = sb;
        out[((size_t)b * 2 + 1) * Npx + p] = sf;
    }
}

extern "C" void kernel_launch(void* const* d_in, const int* in_sizes, int n_in,
                              void* d_out, int out_size, void* d_ws, size_t ws_size,
                              hipStream_t stream) {
    const float* fq = (const float*)d_in[0];
    const float* sf = (const float*)d_in[1];
    const int* mask = (const int*)d_in[2];
    float* out = (float*)d_out;

    float* ws = (float*)d_ws;
    float* FP    = ws;                       // B*C
    float* BP    = FP + Bsz * Cch;
    float* fgp   = BP + Bsz * Cch;
    float* bgp   = fgp + Bsz * Cch;
    float* predf = bgp + Bsz * Cch;          // B*N
    float* predb = predf + Bsz * Npx;
    float* invn  = predb + Bsz * Npx;
    float* wf    = invn + Bsz * Npx;
    float* wb    = wf + Bsz * Npx;
    float* cnts  = wb + Bsz * Npx;           // 16 (fg counts [0..7], bg counts [8..15])
    unsigned short* Gb = (unsigned short*)(cnts + 16);          // B*N*N bf16 (16 MB)
    float* local = (float*)(Gb + (size_t)Bsz * Npx * Npx);      // B*C*N f32 (16 MB)
    unsigned short* Ft = (unsigned short*)(local + (size_t)Bsz * Cch * Npx);  // 8 MB
    unsigned short* Fc = Ft + (size_t)Bsz * Npx * Cch;                        // 8 MB

    k_pool<<<dim3(Cch, Bsz), 256, 0, stream>>>(sf, mask, FP, BP);
    k_pred<<<dim3(Npx / 32, Bsz), 256, 0, stream>>>(fq, FP, BP, predf, predb, invn);
    k_select<<<Bsz, 1024, 0, stream>>>(predf, 0.7f, wf, cnts);
    k_select<<<Bsz, 1024, 0, stream>>>(predb, 0.6f, wb, cnts + Bsz);
    k_proto2<<<dim3(Cch, Bsz), 256, 0, stream>>>(fq, wf, wb, cnts, fgp, bgp);
    k_cast<<<dim3(Npx / 32, Cch / 32, Bsz), 256, 0, stream>>>(fq, Fc, Ft);
    k_gram_mfma<<<dim3(Npx / 128, Npx / 128, Bsz), 256, 0, stream>>>(Ft, Gb);
    k_softmax<<<dim3(Npx, Bsz), 256, 0, stream>>>(Gb, invn, wb);
    k_pv_mfma<<<dim3(Npx / 128, Cch / 64, Bsz), 256, 0, stream>>>(Fc, Gb, local);
    k_out<<<dim3(Npx / 32, Bsz), 256, 0, stream>>>(fq, FP, fgp, bgp, local, out);
}